// Round 5
// baseline (194.167 us; speedup 1.0000x reference)
//
#include <hip/hip_runtime.h>
#include <hip/hip_bf16.h>
#include <math.h>

constexpr int D  = 512;
constexpr int H  = 8;
constexpr int DH = 64;
constexpr int B  = 64;
constexpr int NF = 16384;
constexpr int NO = 8192;
constexpr int NT = NF + NO;
constexpr float EPS = 1e-5f;
constexpr float LOG2E = 1.4426950408889634f;

typedef short short8 __attribute__((ext_vector_type(8)));
typedef float f32x4 __attribute__((ext_vector_type(4)));
typedef unsigned short ushort;
typedef ushort ushort8v __attribute__((ext_vector_type(8)));

__device__ __forceinline__ ushort f2bf(float f) {
  unsigned int x = __float_as_uint(f);
  x += 0x7FFF + ((x >> 16) & 1);   // RNE (inputs finite)
  return (ushort)(x >> 16);
}
__device__ __forceinline__ float bf2f(ushort u) {
  return __uint_as_float(((unsigned int)u) << 16);
}
__device__ __forceinline__ float fast_exp(float x) {   // e^x
  return __builtin_amdgcn_exp2f(x * LOG2E);
}
__device__ __forceinline__ float fast_sigmoid(float z) {
  return __builtin_amdgcn_rcpf(1.0f + __builtin_amdgcn_exp2f(-z * LOG2E));
}
// 8 fp32 -> 8 bf16 (RNE); compiler emits v_cvt_pk_bf16_f32 pairs
__device__ __forceinline__ short8 cvt8(float4 f0, float4 f1) {
  union { short8 v; __hip_bfloat162 h[4]; } u;
  u.h[0] = __float22bfloat162_rn(float2{f0.x, f0.y});
  u.h[1] = __float22bfloat162_rn(float2{f0.z, f0.w});
  u.h[2] = __float22bfloat162_rn(float2{f1.x, f1.y});
  u.h[3] = __float22bfloat162_rn(float2{f1.z, f1.w});
  return u.v;
}

// ---------------- q = ps @ Wq + bq  (64x512), parallel: grid (B,8) ----------------
__global__ __launch_bounds__(256) void k_qproj(const float* __restrict__ ps,
                                               const float* __restrict__ Wq,
                                               const float* __restrict__ bq,
                                               float* __restrict__ q) {
  __shared__ float row[D];
  int b = blockIdx.x, cg = blockIdx.y, t = threadIdx.x;
  for (int i = t; i < D; i += 256) row[i] = ps[(size_t)b * D + i];
  __syncthreads();
  int col = cg * 64 + (t >> 2), eq = t & 3;
  float acc = 0.f;
  const float* wp = Wq + (size_t)(eq * 128) * D + col;
  #pragma unroll 8
  for (int e = 0; e < 128; ++e) acc += row[eq * 128 + e] * wp[(size_t)e * D];
  acc += __shfl_xor(acc, 1); acc += __shfl_xor(acc, 2);
  if (eq == 0) q[(size_t)b * D + col] = acc + bq[col];
}

// ------- Pk[b,h,e] = sum_{c in head h} Wk[e,c]*q[b,c]; qbk[b,h] = sum bk[c]*q[b,c]
__global__ __launch_bounds__(256) void k_pkproj(const float* __restrict__ q,
                                                const float* __restrict__ Wk,
                                                const float* __restrict__ bk,
                                                float* __restrict__ Pk,
                                                float* __restrict__ qbk) {
  int b = blockIdx.x, h = blockIdx.y;
  __shared__ float qs[DH];
  __shared__ float bks[DH];
  int t = threadIdx.x;
  if (t < DH) { qs[t] = q[b * D + h * DH + t]; bks[t] = bk[h * DH + t]; }
  __syncthreads();
  for (int e = t; e < D; e += 256) {
    float acc = 0.f;
    #pragma unroll 8
    for (int j = 0; j < DH; ++j) acc += Wk[(size_t)e * D + h * DH + j] * qs[j];
    Pk[((size_t)b * H + h) * D + e] = acc;
  }
  if (t == 0) {
    float s = 0.f;
    for (int j = 0; j < DH; ++j) s += bks[j] * qs[j];
    qbk[b * H + h] = s;
  }
}

// ------- segment boundaries via binary search (batches are sorted runs) -------
__global__ void k_bounds(const int* __restrict__ fb, const int* __restrict__ ob,
                         int* __restrict__ fstart, int* __restrict__ ostart) {
  int t = threadIdx.x;
  if (t <= B) {
    int lo = 0, hi = NF;
    while (lo < hi) { int mid = (lo + hi) >> 1; if (fb[mid] < t) lo = mid + 1; else hi = mid; }
    fstart[t] = lo;
  } else if (t >= 128 && t <= 128 + B) {
    int v = t - 128;
    int lo = 0, hi = NO;
    while (lo < hi) { int mid = (lo + hi) >> 1; if (ob[mid] < v) lo = mid + 1; else hi = mid; }
    ostart[v] = lo;
  }
}

// ------- scores[n,h] = (nodes[n]·Pk[seg,h] + qbk[seg,h]) / 8 ;  wave per node -------
__global__ __launch_bounds__(256) void k_scores(const float* __restrict__ hf,
                                                const float* __restrict__ ho,
                                                const int* __restrict__ fb,
                                                const int* __restrict__ ob,
                                                const float* __restrict__ Pk,
                                                const float* __restrict__ qbk,
                                                float* __restrict__ scores) {
  int lane = threadIdx.x & 63;
  int n = blockIdx.x * 4 + (threadIdx.x >> 6);
  int b; const float* row;
  if (n < NF) { b = fb[n]; row = hf + (size_t)n * D; }
  else        { b = ob[n - NF]; row = ho + (size_t)(n - NF) * D; }
  const float4* r4 = (const float4*)row;
  float4 x0 = r4[lane * 2], x1 = r4[lane * 2 + 1];
  float acc[H];
  #pragma unroll
  for (int h = 0; h < H; ++h) {
    const float4* p4 = (const float4*)(Pk + ((size_t)b * H + h) * D) + lane * 2;
    float4 p0 = p4[0], p1 = p4[1];
    acc[h] = x0.x * p0.x + x0.y * p0.y + x0.z * p0.z + x0.w * p0.w +
             x1.x * p1.x + x1.y * p1.y + x1.z * p1.z + x1.w * p1.w;
  }
  #pragma unroll
  for (int h = 0; h < H; ++h) {
    float v = acc[h];
    #pragma unroll
    for (int off = 32; off; off >>= 1) v += __shfl_xor(v, off);
    if (lane == h) scores[(size_t)n * H + h] = (v + qbk[b * H + h]) * 0.125f;
  }
}

// ------- per (b,h): segment max, e = exp(s-m), denom -------
__global__ __launch_bounds__(512) void k_segsoftmax(const float* __restrict__ scores,
                                                    const int* __restrict__ fstart,
                                                    const int* __restrict__ ostart,
                                                    float* __restrict__ evals,
                                                    float* __restrict__ denom) {
  int b = blockIdx.x;
  int h = threadIdx.x >> 6, lane = threadIdx.x & 63;
  int f0 = fstart[b], f1 = fstart[b + 1];
  int o0 = ostart[b], o1 = ostart[b + 1];
  float m = -1e30f;
  for (int i = f0 + lane; i < f1; i += 64) m = fmaxf(m, scores[(size_t)i * H + h]);
  for (int i = o0 + lane; i < o1; i += 64) m = fmaxf(m, scores[(size_t)(NF + i) * H + h]);
  #pragma unroll
  for (int off = 32; off; off >>= 1) m = fmaxf(m, __shfl_xor(m, off));
  float s = 0.f;
  for (int i = f0 + lane; i < f1; i += 64) {
    float e = fast_exp(scores[(size_t)i * H + h] - m);
    evals[(size_t)i * H + h] = e; s += e;
  }
  for (int i = o0 + lane; i < o1; i += 64) {
    float e = fast_exp(scores[(size_t)(NF + i) * H + h] - m);
    evals[(size_t)(NF + i) * H + h] = e; s += e;
  }
  #pragma unroll
  for (int off = 32; off; off >>= 1) s += __shfl_xor(s, off);
  if (lane == 0) denom[b * H + h] = s;
}

// ------- T[b,h,e] = sum_{n in seg b} e[n,h]*nodes[n,e] -------
__global__ __launch_bounds__(512) void k_Taccum(const float* __restrict__ hf,
                                                const float* __restrict__ ho,
                                                const int* __restrict__ fstart,
                                                const int* __restrict__ ostart,
                                                const float* __restrict__ evals,
                                                float* __restrict__ T) {
  int b = blockIdx.x, chunk = blockIdx.y;
  int e = threadIdx.x;
  int f0 = fstart[b], flen = fstart[b + 1] - f0;
  int o0 = ostart[b], olen = ostart[b + 1] - o0;
  int L = flen + olen;
  float acc[8] = {0.f, 0.f, 0.f, 0.f, 0.f, 0.f, 0.f, 0.f};
  for (int idx = chunk; idx < L; idx += 8) {
    int n; const float* row;
    if (idx < flen) { n = f0 + idx; row = hf + (size_t)n * D; }
    else            { n = NF + o0 + (idx - flen); row = ho + (size_t)(o0 + idx - flen) * D; }
    float x = row[e];
    const float4* ev = (const float4*)(evals + (size_t)n * H);
    float4 e0 = ev[0], e1 = ev[1];
    acc[0] += e0.x * x; acc[1] += e0.y * x; acc[2] += e0.z * x; acc[3] += e0.w * x;
    acc[4] += e1.x * x; acc[5] += e1.y * x; acc[6] += e1.z * x; acc[7] += e1.w * x;
  }
  #pragma unroll
  for (int h = 0; h < H; ++h) atomicAdd(&T[((size_t)b * H + h) * D + e], acc[h]);
}

// ------- attn[b,c] = (T[b,h(c),:]·Wv[:,c])/denom[b,h] + bv[c]; grid (B,H) -------
__global__ __launch_bounds__(256) void k_attn(const float* __restrict__ T,
                                              const float* __restrict__ denom,
                                              const float* __restrict__ Wv,
                                              const float* __restrict__ bv,
                                              float* __restrict__ attn) {
  __shared__ float Ts[D];
  int b = blockIdx.x, h = blockIdx.y, t = threadIdx.x;
  for (int i = t; i < D; i += 256) Ts[i] = T[((size_t)b * H + h) * D + i];
  __syncthreads();
  int col = h * DH + (t >> 2), eq = t & 3;
  float acc = 0.f;
  const float* wp = Wv + (size_t)(eq * 128) * D + col;
  #pragma unroll 8
  for (int e = 0; e < 128; ++e) acc += Ts[eq * 128 + e] * wp[(size_t)e * D];
  acc += __shfl_xor(acc, 1); acc += __shfl_xor(acc, 2);
  if (eq == 0) attn[(size_t)b * D + col] = acc / denom[b * H + h] + bv[col];
}

// ------- x[b,c] = attn[b,:]·Wo[:,c] + bo[c] + ps[b,c]; grid (B,8) -------
__global__ __launch_bounds__(256) void k_x(const float* __restrict__ attn,
                                           const float* __restrict__ Wo,
                                           const float* __restrict__ bo,
                                           const float* __restrict__ ps,
                                           float* __restrict__ x) {
  __shared__ float As[D];
  int b = blockIdx.x, cg = blockIdx.y, t = threadIdx.x;
  for (int i = t; i < D; i += 256) As[i] = attn[(size_t)b * D + i];
  __syncthreads();
  int col = cg * 64 + (t >> 2), eq = t & 3;
  float acc = 0.f;
  const float* wp = Wo + (size_t)(eq * 128) * D + col;
  #pragma unroll 8
  for (int e = 0; e < 128; ++e) acc += As[eq * 128 + e] * wp[(size_t)e * D];
  acc += __shfl_xor(acc, 1); acc += __shfl_xor(acc, 2);
  if (eq == 0) x[(size_t)b * D + col] = acc + bo[col] + ps[(size_t)b * D + col];
}

// ------- fs = LN(x) per row; grid B, 512 thr -------
__global__ __launch_bounds__(512) void k_ln(const float* __restrict__ x,
                                            float* __restrict__ fs) {
  __shared__ float redS[8], redQ[8];
  __shared__ float sM, sI;
  int b = blockIdx.x, t = threadIdx.x;
  float v = x[(size_t)b * D + t];
  float s = v, sq = v * v;
  #pragma unroll
  for (int off = 32; off; off >>= 1) { s += __shfl_xor(s, off); sq += __shfl_xor(sq, off); }
  int wv = t >> 6, ln = t & 63;
  if (ln == 0) { redS[wv] = s; redQ[wv] = sq; }
  __syncthreads();
  if (t == 0) {
    float S = 0.f, Q = 0.f;
    #pragma unroll
    for (int i = 0; i < 8; ++i) { S += redS[i]; Q += redQ[i]; }
    float mean = S * (1.f / D);
    float var = Q * (1.f / D) - mean * mean;
    sM = mean; sI = rsqrtf(var + EPS);
  }
  __syncthreads();
  fs[(size_t)b * D + t] = (v - sM) * sI;
}

// ------- Wgt[c][k] = bf16(Wg[k][c]) -------
__global__ __launch_bounds__(256) void k_prepW(const float* __restrict__ Wg,
                                               ushort* __restrict__ Wgt) {
  __shared__ float tile[32][33];
  int bx = blockIdx.x, by = blockIdx.y;
  int tx = threadIdx.x & 31, ty = threadIdx.x >> 5;  // ty: 0..7
  #pragma unroll
  for (int i = 0; i < 4; ++i)
    tile[ty + i * 8][tx] = Wg[(size_t)(by * 32 + ty + i * 8) * D + bx * 32 + tx];
  __syncthreads();
  #pragma unroll
  for (int i = 0; i < 4; ++i)
    Wgt[(size_t)(bx * 32 + ty + i * 8) * D + by * 32 + tx] = f2bf(tile[tx][ty + i * 8]);
}

// ------- fused: gate = sigmoid(hf@Wg+bg); out = LN(hf + gate*(alpha*fs[fb])) -------
// 32 rows x 512 cols per block; 512 blocks (4/CU by LDS=34KB), 4 waves x 128 cols.
// NO barriers in K-loop: each wave loads A (fp32->cvt_pk bf16) and B (bf16 Wg^T)
// directly from global; MFMA streams independently per wave.
__global__ __launch_bounds__(256, 4) void k_gate_ln(const float* __restrict__ hf,
                                                    const ushort* __restrict__ Wgt,
                                                    const float* __restrict__ bg,
                                                    const float* __restrict__ alpha,
                                                    const float* __restrict__ fs,
                                                    const int* __restrict__ fb,
                                                    float* __restrict__ out) {
  __shared__ ushort gls[32][544];    // bf16 gate tile, XOR-swizzled 8-col blocks
  const int tid = threadIdx.x;
  const int lane = tid & 63, w = tid >> 6;       // 4 waves
  const int rowBase = blockIdx.x * 32;
  const int lrow = lane & 15, kg = lane >> 4;

  const float*  Ap = hf  + (size_t)(rowBase + lrow) * D + kg * 8;
  const ushort* Bp = Wgt + (size_t)(w * 128 + lrow) * D + kg * 8;

  f32x4 acc[2][8] = {};
  #pragma unroll 4
  for (int step = 0; step < 16; ++step) {
    short8 a[2], b[8];
    #pragma unroll
    for (int m = 0; m < 2; ++m) {
      const float* p = Ap + (size_t)m * 16 * D + step * 32;
      a[m] = cvt8(*(const float4*)p, *(const float4*)(p + 4));
    }
    #pragma unroll
    for (int n = 0; n < 8; ++n)
      b[n] = *(const short8*)(Bp + (size_t)n * 16 * D + step * 32);
    #pragma unroll
    for (int m = 0; m < 2; ++m)
      #pragma unroll
      for (int n = 0; n < 8; ++n)
        acc[m][n] = __builtin_amdgcn_mfma_f32_16x16x32_bf16(a[m], b[n], acc[m][n], 0, 0, 0);
  }

  // phase 1: sigmoid -> swizzled bf16 LDS.  C/D map: col=lane&15, row=(lane>>4)*4+reg
  #pragma unroll
  for (int n = 0; n < 8; ++n) {
    int col = w * 128 + n * 16 + lrow;
    float bgv = bg[col];
    int colblk = col >> 3;
    int sblk = colblk ^ (colblk >> 3);
    #pragma unroll
    for (int m = 0; m < 2; ++m) {
      #pragma unroll
      for (int r = 0; r < 4; ++r) {
        int rib = m * 16 + kg * 4 + r;
        float g = fast_sigmoid(acc[m][n][r] + bgv);
        ((ushort*)gls)[rib * 544 + sblk * 8 + (col & 7)] = f2bf(g);
      }
    }
  }
  __syncthreads();

  // phase 2: per-row residual + LN, vectorized (8 threads per row, 64 cols each)
  const int row = tid >> 3, cg = tid & 7;
  const int grow = rowBase + row;
  const int bidx = fb[grow];
  const float* hfr = hf + (size_t)grow * D + cg * 64;
  const float* fsr = fs + (size_t)bidx * D + cg * 64;
  const float* alr = alpha + cg * 64;
  float x[64];
  float s = 0.f, sq = 0.f;
  #pragma unroll
  for (int jb = 0; jb < 8; ++jb) {
    int sblk = (cg * 8 + jb) ^ cg;
    union { ushort8v v; ushort u[8]; } ug;
    ug.v = *(const ushort8v*)((const ushort*)gls + row * 544 + sblk * 8);
    float4 h0 = *(const float4*)(hfr + jb * 8);
    float4 h1 = *(const float4*)(hfr + jb * 8 + 4);
    float4 p0 = *(const float4*)(fsr + jb * 8);
    float4 p1 = *(const float4*)(fsr + jb * 8 + 4);
    float4 a0 = *(const float4*)(alr + jb * 8);
    float4 a1 = *(const float4*)(alr + jb * 8 + 4);
    float hv[8] = {h0.x, h0.y, h0.z, h0.w, h1.x, h1.y, h1.z, h1.w};
    float pv[8] = {p0.x, p0.y, p0.z, p0.w, p1.x, p1.y, p1.z, p1.w};
    float av[8] = {a0.x, a0.y, a0.z, a0.w, a1.x, a1.y, a1.z, a1.w};
    #pragma unroll
    for (int i = 0; i < 8; ++i) {
      float xv = hv[i] + bf2f(ug.u[i]) * (av[i] * pv[i]);
      x[jb * 8 + i] = xv; s += xv; sq += xv * xv;
    }
  }
  #pragma unroll
  for (int off = 1; off < 8; off <<= 1) { s += __shfl_xor(s, off); sq += __shfl_xor(sq, off); }
  float mean = s * (1.f / D);
  float inv = rsqrtf(sq * (1.f / D) - mean * mean + EPS);
  float* op = out + (size_t)grow * D + cg * 64;
  #pragma unroll
  for (int j4 = 0; j4 < 16; ++j4) {
    float4 o = { (x[j4 * 4 + 0] - mean) * inv, (x[j4 * 4 + 1] - mean) * inv,
                 (x[j4 * 4 + 2] - mean) * inv, (x[j4 * 4 + 3] - mean) * inv };
    *(float4*)(op + j4 * 4) = o;
  }
}

extern "C" void kernel_launch(void* const* d_in, const int* in_sizes, int n_in,
                              void* d_out, int out_size, void* d_ws, size_t ws_size,
                              hipStream_t stream) {
  const float* hf    = (const float*)d_in[0];
  const float* ho    = (const float*)d_in[1];
  const float* ps    = (const float*)d_in[2];
  const int*   fb    = (const int*)d_in[3];
  const int*   ob    = (const int*)d_in[4];
  const float* Wq    = (const float*)d_in[5];
  const float* bq    = (const float*)d_in[6];
  const float* Wk    = (const float*)d_in[7];
  const float* bk    = (const float*)d_in[8];
  const float* Wv    = (const float*)d_in[9];
  const float* bv    = (const float*)d_in[10];
  const float* Wo    = (const float*)d_in[11];
  const float* bo    = (const float*)d_in[12];
  const float* Wg    = (const float*)d_in[13];
  const float* bg    = (const float*)d_in[14];
  const float* alpha = (const float*)d_in[15];

  float* out    = (float*)d_out;
  float* fs_out = out + (size_t)NF * D;

  ushort* Wgt   = (ushort*)d_ws;                    // 512KB bf16 Wg^T
  float* ws     = (float*)d_ws + (512 * 512 * 2) / 4;
  float* q      = ws;                      // B*D
  float* Pk     = q + B * D;               // B*H*D
  float* qbk    = Pk + B * H * D;          // B*H
  float* scores = qbk + B * H;             // NT*H
  float* evals  = scores + (size_t)NT * H; // NT*H
  float* denom  = evals + (size_t)NT * H;  // B*H
  float* T      = denom + B * H;           // B*H*D
  float* attn   = T + B * H * D;           // B*D
  float* xbuf   = attn + B * D;            // B*D
  int* fstart   = (int*)(xbuf + B * D);    // B+1
  int* ostart   = fstart + (B + 1);        // B+1

  k_prepW<<<dim3(16, 16), 256, 0, stream>>>(Wg, Wgt);
  k_qproj<<<dim3(B, 8), 256, 0, stream>>>(ps, Wq, bq, q);
  k_pkproj<<<dim3(B, H), 256, 0, stream>>>(q, Wk, bk, Pk, qbk);
  k_bounds<<<1, 256, 0, stream>>>(fb, ob, fstart, ostart);
  hipMemsetAsync(T, 0, (size_t)B * H * D * sizeof(float), stream);
  k_scores<<<NT / 4, 256, 0, stream>>>(hf, ho, fb, ob, Pk, qbk, scores);
  k_segsoftmax<<<B, 512, 0, stream>>>(scores, fstart, ostart, evals, denom);
  k_Taccum<<<dim3(B, 8), 512, 0, stream>>>(hf, ho, fstart, ostart, evals, T);
  k_attn<<<dim3(B, H), 256, 0, stream>>>(T, denom, Wv, bv, attn);
  k_x<<<dim3(B, 8), 256, 0, stream>>>(attn, Wo, bo, ps, xbuf);
  k_ln<<<B, 512, 0, stream>>>(xbuf, fs_out);
  k_gate_ln<<<NF / 32, 256, 0, stream>>>(hf, Wgt, bg, alpha, fs_out, fb, out);
}

// Round 6
// 146.901 us; speedup vs baseline: 1.3218x; 1.3218x over previous
//
#include <hip/hip_runtime.h>
#include <hip/hip_bf16.h>
#include <math.h>

constexpr int D  = 512;
constexpr int H  = 8;
constexpr int DH = 64;
constexpr int B  = 64;
constexpr int NF = 16384;
constexpr int NO = 8192;
constexpr int NT = NF + NO;
constexpr float EPS = 1e-5f;
constexpr float LOG2E = 1.4426950408889634f;

typedef short short8 __attribute__((ext_vector_type(8)));
typedef float f32x4 __attribute__((ext_vector_type(4)));
typedef unsigned short ushort;
typedef ushort ushort8v __attribute__((ext_vector_type(8)));

__device__ __forceinline__ ushort f2bf(float f) {
  unsigned int x = __float_as_uint(f);
  x += 0x7FFF + ((x >> 16) & 1);   // RNE (inputs finite)
  return (ushort)(x >> 16);
}
__device__ __forceinline__ float bf2f(ushort u) {
  return __uint_as_float(((unsigned int)u) << 16);
}
__device__ __forceinline__ float fast_exp(float x) {   // e^x
  return __builtin_amdgcn_exp2f(x * LOG2E);
}
__device__ __forceinline__ float fast_sigmoid(float z) {
  return __builtin_amdgcn_rcpf(1.0f + __builtin_amdgcn_exp2f(-z * LOG2E));
}
// 8 fp32 -> 8 bf16 (RNE); compiler emits v_cvt_pk_bf16_f32 pairs
__device__ __forceinline__ short8 cvt8(float4 f0, float4 f1) {
  union { short8 v; __hip_bfloat162 h[4]; } u;
  u.h[0] = __float22bfloat162_rn(float2{f0.x, f0.y});
  u.h[1] = __float22bfloat162_rn(float2{f0.z, f0.w});
  u.h[2] = __float22bfloat162_rn(float2{f1.x, f1.y});
  u.h[3] = __float22bfloat162_rn(float2{f1.z, f1.w});
  return u.v;
}
// async global->LDS, 16B per lane; lds dest = wave-uniform base + lane*16
__device__ __forceinline__ void gll16(const void* g, void* l) {
  __builtin_amdgcn_global_load_lds(
      (const __attribute__((address_space(1))) void*)g,
      (__attribute__((address_space(3))) void*)l, 16, 0, 0);
}

// ---------------- q = ps @ Wq + bq  (64x512), parallel: grid (B,8) ----------------
__global__ __launch_bounds__(256) void k_qproj(const float* __restrict__ ps,
                                               const float* __restrict__ Wq,
                                               const float* __restrict__ bq,
                                               float* __restrict__ q) {
  __shared__ float row[D];
  int b = blockIdx.x, cg = blockIdx.y, t = threadIdx.x;
  for (int i = t; i < D; i += 256) row[i] = ps[(size_t)b * D + i];
  __syncthreads();
  int col = cg * 64 + (t >> 2), eq = t & 3;
  float acc = 0.f;
  const float* wp = Wq + (size_t)(eq * 128) * D + col;
  #pragma unroll 8
  for (int e = 0; e < 128; ++e) acc += row[eq * 128 + e] * wp[(size_t)e * D];
  acc += __shfl_xor(acc, 1); acc += __shfl_xor(acc, 2);
  if (eq == 0) q[(size_t)b * D + col] = acc + bq[col];
}

// ------- Pk[b,h,e] = sum_{c in head h} Wk[e,c]*q[b,c]; qbk[b,h] = sum bk[c]*q[b,c]
__global__ __launch_bounds__(256) void k_pkproj(const float* __restrict__ q,
                                                const float* __restrict__ Wk,
                                                const float* __restrict__ bk,
                                                float* __restrict__ Pk,
                                                float* __restrict__ qbk) {
  int b = blockIdx.x, h = blockIdx.y;
  __shared__ float qs[DH];
  __shared__ float bks[DH];
  int t = threadIdx.x;
  if (t < DH) { qs[t] = q[b * D + h * DH + t]; bks[t] = bk[h * DH + t]; }
  __syncthreads();
  for (int e = t; e < D; e += 256) {
    float acc = 0.f;
    #pragma unroll 8
    for (int j = 0; j < DH; ++j) acc += Wk[(size_t)e * D + h * DH + j] * qs[j];
    Pk[((size_t)b * H + h) * D + e] = acc;
  }
  if (t == 0) {
    float s = 0.f;
    for (int j = 0; j < DH; ++j) s += bks[j] * qs[j];
    qbk[b * H + h] = s;
  }
}

// ------- segment boundaries via binary search (batches are sorted runs) -------
__global__ void k_bounds(const int* __restrict__ fb, const int* __restrict__ ob,
                         int* __restrict__ fstart, int* __restrict__ ostart) {
  int t = threadIdx.x;
  if (t <= B) {
    int lo = 0, hi = NF;
    while (lo < hi) { int mid = (lo + hi) >> 1; if (fb[mid] < t) lo = mid + 1; else hi = mid; }
    fstart[t] = lo;
  } else if (t >= 128 && t <= 128 + B) {
    int v = t - 128;
    int lo = 0, hi = NO;
    while (lo < hi) { int mid = (lo + hi) >> 1; if (ob[mid] < v) lo = mid + 1; else hi = mid; }
    ostart[v] = lo;
  }
}

// ------- scores[n,h] = (nodes[n]·Pk[seg,h] + qbk[seg,h]) / 8 ;  wave per node -------
__global__ __launch_bounds__(256) void k_scores(const float* __restrict__ hf,
                                                const float* __restrict__ ho,
                                                const int* __restrict__ fb,
                                                const int* __restrict__ ob,
                                                const float* __restrict__ Pk,
                                                const float* __restrict__ qbk,
                                                float* __restrict__ scores) {
  int lane = threadIdx.x & 63;
  int n = blockIdx.x * 4 + (threadIdx.x >> 6);
  int b; const float* row;
  if (n < NF) { b = fb[n]; row = hf + (size_t)n * D; }
  else        { b = ob[n - NF]; row = ho + (size_t)(n - NF) * D; }
  const float4* r4 = (const float4*)row;
  float4 x0 = r4[lane * 2], x1 = r4[lane * 2 + 1];
  float acc[H];
  #pragma unroll
  for (int h = 0; h < H; ++h) {
    const float4* p4 = (const float4*)(Pk + ((size_t)b * H + h) * D) + lane * 2;
    float4 p0 = p4[0], p1 = p4[1];
    acc[h] = x0.x * p0.x + x0.y * p0.y + x0.z * p0.z + x0.w * p0.w +
             x1.x * p1.x + x1.y * p1.y + x1.z * p1.z + x1.w * p1.w;
  }
  #pragma unroll
  for (int h = 0; h < H; ++h) {
    float v = acc[h];
    #pragma unroll
    for (int off = 32; off; off >>= 1) v += __shfl_xor(v, off);
    if (lane == h) scores[(size_t)n * H + h] = (v + qbk[b * H + h]) * 0.125f;
  }
}

// ------- per (b,h): segment max, e = exp(s-m), denom -------
__global__ __launch_bounds__(512) void k_segsoftmax(const float* __restrict__ scores,
                                                    const int* __restrict__ fstart,
                                                    const int* __restrict__ ostart,
                                                    float* __restrict__ evals,
                                                    float* __restrict__ denom) {
  int b = blockIdx.x;
  int h = threadIdx.x >> 6, lane = threadIdx.x & 63;
  int f0 = fstart[b], f1 = fstart[b + 1];
  int o0 = ostart[b], o1 = ostart[b + 1];
  float m = -1e30f;
  for (int i = f0 + lane; i < f1; i += 64) m = fmaxf(m, scores[(size_t)i * H + h]);
  for (int i = o0 + lane; i < o1; i += 64) m = fmaxf(m, scores[(size_t)(NF + i) * H + h]);
  #pragma unroll
  for (int off = 32; off; off >>= 1) m = fmaxf(m, __shfl_xor(m, off));
  float s = 0.f;
  for (int i = f0 + lane; i < f1; i += 64) {
    float e = fast_exp(scores[(size_t)i * H + h] - m);
    evals[(size_t)i * H + h] = e; s += e;
  }
  for (int i = o0 + lane; i < o1; i += 64) {
    float e = fast_exp(scores[(size_t)(NF + i) * H + h] - m);
    evals[(size_t)(NF + i) * H + h] = e; s += e;
  }
  #pragma unroll
  for (int off = 32; off; off >>= 1) s += __shfl_xor(s, off);
  if (lane == 0) denom[b * H + h] = s;
}

// ------- T8[chunk][b][h][e] = sum_{n in chunk of seg b} e[n,h]*nodes[n,e]; no atomics ----
__global__ __launch_bounds__(512) void k_Taccum(const float* __restrict__ hf,
                                                const float* __restrict__ ho,
                                                const int* __restrict__ fstart,
                                                const int* __restrict__ ostart,
                                                const float* __restrict__ evals,
                                                float* __restrict__ T8) {
  int b = blockIdx.x, chunk = blockIdx.y;
  int e = threadIdx.x;
  int f0 = fstart[b], flen = fstart[b + 1] - f0;
  int o0 = ostart[b], olen = ostart[b + 1] - o0;
  int L = flen + olen;
  float acc[8] = {0.f, 0.f, 0.f, 0.f, 0.f, 0.f, 0.f, 0.f};
  for (int idx = chunk; idx < L; idx += 8) {
    int n; const float* row;
    if (idx < flen) { n = f0 + idx; row = hf + (size_t)n * D; }
    else            { n = NF + o0 + (idx - flen); row = ho + (size_t)(o0 + idx - flen) * D; }
    float x = row[e];
    const float4* ev = (const float4*)(evals + (size_t)n * H);
    float4 e0 = ev[0], e1 = ev[1];
    acc[0] += e0.x * x; acc[1] += e0.y * x; acc[2] += e0.z * x; acc[3] += e0.w * x;
    acc[4] += e1.x * x; acc[5] += e1.y * x; acc[6] += e1.z * x; acc[7] += e1.w * x;
  }
  #pragma unroll
  for (int h = 0; h < H; ++h)
    T8[(((size_t)chunk * B + b) * H + h) * D + e] = acc[h];
}

// ------- attn[b,c] = (sumT8·Wv)/denom + bv; grid (B,H) -------
__global__ __launch_bounds__(256) void k_attn(const float* __restrict__ T8,
                                              const float* __restrict__ denom,
                                              const float* __restrict__ Wv,
                                              const float* __restrict__ bv,
                                              float* __restrict__ attn) {
  __shared__ float Ts[D];
  int b = blockIdx.x, h = blockIdx.y, t = threadIdx.x;
  for (int i = t; i < D; i += 256) {
    float s = 0.f;
    #pragma unroll
    for (int c2 = 0; c2 < 8; ++c2)
      s += T8[(((size_t)c2 * B + b) * H + h) * D + i];
    Ts[i] = s;
  }
  __syncthreads();
  int col = h * DH + (t >> 2), eq = t & 3;
  float acc = 0.f;
  const float* wp = Wv + (size_t)(eq * 128) * D + col;
  #pragma unroll 8
  for (int e = 0; e < 128; ++e) acc += Ts[eq * 128 + e] * wp[(size_t)e * D];
  acc += __shfl_xor(acc, 1); acc += __shfl_xor(acc, 2);
  if (eq == 0) attn[(size_t)b * D + col] = acc / denom[b * H + h] + bv[col];
}

// ------- x[b,c] = attn[b,:]·Wo[:,c] + bo[c] + ps[b,c]; grid (B,8) -------
__global__ __launch_bounds__(256) void k_x(const float* __restrict__ attn,
                                           const float* __restrict__ Wo,
                                           const float* __restrict__ bo,
                                           const float* __restrict__ ps,
                                           float* __restrict__ x) {
  __shared__ float As[D];
  int b = blockIdx.x, cg = blockIdx.y, t = threadIdx.x;
  for (int i = t; i < D; i += 256) As[i] = attn[(size_t)b * D + i];
  __syncthreads();
  int col = cg * 64 + (t >> 2), eq = t & 3;
  float acc = 0.f;
  const float* wp = Wo + (size_t)(eq * 128) * D + col;
  #pragma unroll 8
  for (int e = 0; e < 128; ++e) acc += As[eq * 128 + e] * wp[(size_t)e * D];
  acc += __shfl_xor(acc, 1); acc += __shfl_xor(acc, 2);
  if (eq == 0) x[(size_t)b * D + col] = acc + bo[col] + ps[(size_t)b * D + col];
}

// ------- fs = LN(x) per row; grid B, 512 thr -------
__global__ __launch_bounds__(512) void k_ln(const float* __restrict__ x,
                                            float* __restrict__ fs) {
  __shared__ float redS[8], redQ[8];
  __shared__ float sM, sI;
  int b = blockIdx.x, t = threadIdx.x;
  float v = x[(size_t)b * D + t];
  float s = v, sq = v * v;
  #pragma unroll
  for (int off = 32; off; off >>= 1) { s += __shfl_xor(s, off); sq += __shfl_xor(sq, off); }
  int wv = t >> 6, ln = t & 63;
  if (ln == 0) { redS[wv] = s; redQ[wv] = sq; }
  __syncthreads();
  if (t == 0) {
    float S = 0.f, Q = 0.f;
    #pragma unroll
    for (int i = 0; i < 8; ++i) { S += redS[i]; Q += redQ[i]; }
    float mean = S * (1.f / D);
    float var = Q * (1.f / D) - mean * mean;
    sM = mean; sI = rsqrtf(var + EPS);
  }
  __syncthreads();
  fs[(size_t)b * D + t] = (v - sM) * sI;
}

// ------- Wgt[c][k] = bf16(Wg[k][c]) -------
__global__ __launch_bounds__(256) void k_prepW(const float* __restrict__ Wg,
                                               ushort* __restrict__ Wgt) {
  __shared__ float tile[32][33];
  int bx = blockIdx.x, by = blockIdx.y;
  int tx = threadIdx.x & 31, ty = threadIdx.x >> 5;  // ty: 0..7
  #pragma unroll
  for (int i = 0; i < 4; ++i)
    tile[ty + i * 8][tx] = Wg[(size_t)(by * 32 + ty + i * 8) * D + bx * 32 + tx];
  __syncthreads();
  #pragma unroll
  for (int i = 0; i < 4; ++i)
    Wgt[(size_t)(bx * 32 + ty + i * 8) * D + by * 32 + tx] = f2bf(tile[tx][ty + i * 8]);
}

// ------- gate GEMM: gateb = bf16(sigmoid(hf @ Wg + bg)), m97-style 128x128, BK=32 ----
// A fp32 staged via global_load_lds w/ chunk-XOR (row&7, 8 chunks/row);
// B bf16 staged via global_load_lds w/ chunk-XOR ((col>>1)&3, 4 chunks/row).
// 4 waves (2Mx2N quadrants of 64x64), 16 K-steps, 1 barrier/step.
__global__ __launch_bounds__(256) void k_gate(const float* __restrict__ hf,
                                              const ushort* __restrict__ Wgt,
                                              const float* __restrict__ bg,
                                              ushort* __restrict__ gateb) {
  __shared__ float  Asf[2][4096];   // 16KB per buf: [128 rows][32 k] fp32, chunk-swizzled
  __shared__ ushort Bs[2][4096];    // 8KB per buf: [128 cols][32 k] bf16, chunk-swizzled
  const int tid = threadIdx.x, lane = tid & 63, w = tid >> 6;
  const int rowBase = blockIdx.x * 128, colBase = blockIdx.y * 128;
  const int wm = w >> 1, wn = w & 1;
  const int lrow = lane & 15, kg = lane >> 4;

  // staging lanes: A -> 4 issues/wave, B -> 2 issues/wave
  int ia[4], ra[4], ca[4];
  #pragma unroll
  for (int j = 0; j < 4; ++j) {
    ia[j] = (w * 4 + j) * 64 + lane;
    ra[j] = ia[j] >> 3;
    ca[j] = (ia[j] & 7) ^ (ra[j] & 7);
  }
  int ib[2], cb[2], cc[2];
  #pragma unroll
  for (int j = 0; j < 2; ++j) {
    ib[j] = (w * 2 + j) * 64 + lane;
    cb[j] = ib[j] >> 2;
    cc[j] = (ib[j] & 3) ^ ((cb[j] >> 1) & 3);
  }

#define STAGE(buf, k0)                                                          \
  {                                                                             \
    _Pragma("unroll")                                                           \
    for (int j = 0; j < 4; ++j)                                                 \
      gll16(hf + (size_t)(rowBase + ra[j]) * D + (k0) + ca[j] * 4,              \
            &Asf[buf][(w * 4 + j) * 256]);                                      \
    _Pragma("unroll")                                                           \
    for (int j = 0; j < 2; ++j)                                                 \
      gll16(Wgt + (size_t)(colBase + cb[j]) * D + (k0) + cc[j] * 8,             \
            &Bs[buf][(w * 2 + j) * 512]);                                       \
  }

  STAGE(0, 0);
  __syncthreads();

  f32x4 acc[4][4] = {};
  for (int t = 0; t < 16; ++t) {
    const int cur = t & 1;
    if (t < 15) STAGE(cur ^ 1, (t + 1) * 32);
    short8 av[4], bv[4];
    #pragma unroll
    for (int m = 0; m < 4; ++m) {
      const int a_r = wm * 64 + m * 16 + lrow;
      const float* Ab = &Asf[cur][a_r * 32];
      const int c0 = (2 * kg) ^ (a_r & 7), c1 = (2 * kg + 1) ^ (a_r & 7);
      av[m] = cvt8(*(const float4*)(Ab + c0 * 4), *(const float4*)(Ab + c1 * 4));
    }
    #pragma unroll
    for (int n = 0; n < 4; ++n) {
      const int b_c = wn * 64 + n * 16 + lrow;
      bv[n] = *(const short8*)&Bs[cur][b_c * 32 + (kg ^ ((b_c >> 1) & 3)) * 8];
    }
    #pragma unroll
    for (int m = 0; m < 4; ++m)
      #pragma unroll
      for (int n = 0; n < 4; ++n)
        acc[m][n] = __builtin_amdgcn_mfma_f32_16x16x32_bf16(av[m], bv[n], acc[m][n], 0, 0, 0);
    __syncthreads();
  }
#undef STAGE

  // epilogue: sigmoid + bias -> bf16 global.  C/D map: col=lane&15, row=(lane>>4)*4+reg
  #pragma unroll
  for (int n = 0; n < 4; ++n) {
    const int col = colBase + wn * 64 + n * 16 + lrow;
    const float bgv = bg[col];
    #pragma unroll
    for (int m = 0; m < 4; ++m) {
      const int row0 = rowBase + wm * 64 + m * 16 + kg * 4;
      #pragma unroll
      for (int r = 0; r < 4; ++r)
        gateb[(size_t)(row0 + r) * D + col] = f2bf(fast_sigmoid(acc[m][n][r] + bgv));
    }
  }
}

// ------- out = LN(hf + gate*(alpha*fs[fb])); 1 wave/row, grid NF/4 -------
__global__ __launch_bounds__(256) void k_final(const float* __restrict__ hf,
                                               const ushort* __restrict__ gateb,
                                               const float* __restrict__ alpha,
                                               const float* __restrict__ fs,
                                               const int* __restrict__ fb,
                                               float* __restrict__ out) {
  const int w = threadIdx.x >> 6, lane = threadIdx.x & 63;
  const int row = blockIdx.x * 4 + w;
  const int b = fb[row];
  const float* hr = hf + (size_t)row * D + lane * 8;
  const ushort* gr = gateb + (size_t)row * D + lane * 8;
  const float* fr = fs + (size_t)b * D + lane * 8;
  const float* ar = alpha + lane * 8;
  float4 h0 = *(const float4*)hr, h1 = *(const float4*)(hr + 4);
  union { ushort8v v; ushort u[8]; } ug;
  ug.v = *(const ushort8v*)gr;
  float4 p0 = *(const float4*)fr, p1 = *(const float4*)(fr + 4);
  float4 a0 = *(const float4*)ar, a1 = *(const float4*)(ar + 4);
  float hv[8] = {h0.x, h0.y, h0.z, h0.w, h1.x, h1.y, h1.z, h1.w};
  float pv[8] = {p0.x, p0.y, p0.z, p0.w, p1.x, p1.y, p1.z, p1.w};
  float av[8] = {a0.x, a0.y, a0.z, a0.w, a1.x, a1.y, a1.z, a1.w};
  float x[8], s = 0.f, sq = 0.f;
  #pragma unroll
  for (int i = 0; i < 8; ++i) {
    x[i] = hv[i] + bf2f(ug.u[i]) * (av[i] * pv[i]);
    s += x[i]; sq += x[i] * x[i];
  }
  #pragma unroll
  for (int off = 32; off; off >>= 1) { s += __shfl_xor(s, off); sq += __shfl_xor(sq, off); }
  float mean = s * (1.f / D);
  float inv = rsqrtf(sq * (1.f / D) - mean * mean + EPS);
  float* op = out + (size_t)row * D + lane * 8;
  float4 o0 = {(x[0] - mean) * inv, (x[1] - mean) * inv, (x[2] - mean) * inv, (x[3] - mean) * inv};
  float4 o1 = {(x[4] - mean) * inv, (x[5] - mean) * inv, (x[6] - mean) * inv, (x[7] - mean) * inv};
  *(float4*)op = o0;
  *(float4*)(op + 4) = o1;
}

extern "C" void kernel_launch(void* const* d_in, const int* in_sizes, int n_in,
                              void* d_out, int out_size, void* d_ws, size_t ws_size,
                              hipStream_t stream) {
  const float* hf    = (const float*)d_in[0];
  const float* ho    = (const float*)d_in[1];
  const float* ps    = (const float*)d_in[2];
  const int*   fb    = (const int*)d_in[3];
  const int*   ob    = (const int*)d_in[4];
  const float* Wq    = (const float*)d_in[5];
  const float* bq    = (const float*)d_in[6];
  const float* Wk    = (const float*)d_in[7];
  const float* bk    = (const float*)d_in[8];
  const float* Wv    = (const float*)d_in[9];
  const float* bv    = (const float*)d_in[10];
  const float* Wo    = (const float*)d_in[11];
  const float* bo    = (const float*)d_in[12];
  const float* Wg    = (const float*)d_in[13];
  const float* bg    = (const float*)d_in[14];
  const float* alpha = (const float*)d_in[15];

  float* out    = (float*)d_out;
  float* fs_out = out + (size_t)NF * D;

  ushort* Wgt   = (ushort*)d_ws;                    // 512KB bf16 Wg^T
  ushort* gateb = Wgt + 512 * 512;                  // 16MB bf16 gate
  float* fbase  = (float*)(gateb + (size_t)NF * D);
  float* q      = fbase;                   // B*D
  float* Pk     = q + B * D;               // B*H*D
  float* qbk    = Pk + B * H * D;          // B*H
  float* scores = qbk + B * H;             // NT*H
  float* evals  = scores + (size_t)NT * H; // NT*H
  float* denom  = evals + (size_t)NT * H;  // B*H
  float* T8     = denom + B * H;           // 8*B*H*D (8MB)
  float* attn   = T8 + (size_t)8 * B * H * D; // B*D
  float* xbuf   = attn + B * D;            // B*D
  int* fstart   = (int*)(xbuf + B * D);    // B+1
  int* ostart   = fstart + (B + 1);        // B+1

  k_prepW<<<dim3(16, 16), 256, 0, stream>>>(Wg, Wgt);
  k_gate<<<dim3(NF / 128, 4), 256, 0, stream>>>(hf, Wgt, bg, gateb);
  k_qproj<<<dim3(B, 8), 256, 0, stream>>>(ps, Wq, bq, q);
  k_pkproj<<<dim3(B, H), 256, 0, stream>>>(q, Wk, bk, Pk, qbk);
  k_bounds<<<1, 256, 0, stream>>>(fb, ob, fstart, ostart);
  k_scores<<<NT / 4, 256, 0, stream>>>(hf, ho, fb, ob, Pk, qbk, scores);
  k_segsoftmax<<<B, 512, 0, stream>>>(scores, fstart, ostart, evals, denom);
  k_Taccum<<<dim3(B, 8), 512, 0, stream>>>(hf, ho, fstart, ostart, evals, T8);
  k_attn<<<dim3(B, H), 256, 0, stream>>>(T8, denom, Wv, bv, attn);
  k_x<<<dim3(B, 8), 256, 0, stream>>>(attn, Wo, bo, ps, xbuf);
  k_ln<<<B, 512, 0, stream>>>(xbuf, fs_out);
  k_final<<<NF / 4, 256, 0, stream>>>(hf, gateb, alpha, fs_out, fb, out);
}